// Round 2
// baseline (423.981 us; speedup 1.0000x reference)
//
#include <hip/hip_runtime.h>
#include <math.h>

#define BB 1024
#define LSx 128
#define LLx 2048
#define TOPKx 48
#define VOCABx 160000

// ---------------------------------------------------------------------------
// Kernel A: precompute partial LSH projections
//   P[v][seg][m] = sum_e emb[v][e] * H[seg*16+e][m]   (v*48 + seg*16 + m)
// ---------------------------------------------------------------------------
__global__ __launch_bounds__(256) void k_partial(
    const float* __restrict__ emb, const float* __restrict__ Hm,
    float* __restrict__ P)
{
  const int idx = blockIdx.x * 256 + threadIdx.x;   // = v*48 + seg*16 + m
  if (idx >= VOCABx * 48) return;
  const int v = idx / 48;
  const int r = idx - v * 48;
  const int seg = r >> 4, m = r & 15;
  const float* er = emb + (size_t)v * 16;
  float a = 0.f;
  #pragma unroll
  for (int e = 0; e < 16; ++e) a += er[e] * Hm[(seg * 16 + e) * 16 + m];
  P[idx] = a;
}

// ---------------------------------------------------------------------------
// Kernel B: LSH scoring + top-k selection (one 512-thread block per batch elem)
// ---------------------------------------------------------------------------
__global__ __launch_bounds__(512) void k_score_topk(
    const int* __restrict__ lg, const int* __restrict__ lsh, const int* __restrict__ lc,
    const int* __restrict__ ig, const int* __restrict__ ish, const int* __restrict__ ici,
    const float* __restrict__ P,
    int* __restrict__ sel)
{
  __shared__ signed char scores[LLx];
  __shared__ int hist[18];
  __shared__ int icode[16];
  __shared__ int cnt_above;
  __shared__ int wsum[8];
  const int b = blockIdx.x, tid = threadIdx.x;

  if (tid < 18) hist[tid] = 0;
  if (tid == 0) cnt_above = 0;
  if (tid < 16) {
    const float d = P[(size_t)ig[b] * 48 + tid]
                  + P[(size_t)ish[b] * 48 + 16 + tid]
                  + P[(size_t)ici[b] * 48 + 32 + tid];
    icode[tid] = (d > 0.f) ? 1 : (d < 0.f ? -1 : 0);
  }
  __syncthreads();

  // ---- scoring: thread handles 4 consecutive positions (int4 id loads) ----
  const int base_l = tid * 4;
  const int4 g4 = ((const int4*)(lg + (size_t)b * LLx))[tid];
  const int4 s4 = ((const int4*)(lsh + (size_t)b * LLx))[tid];
  const int4 c4 = ((const int4*)(lc + (size_t)b * LLx))[tid];
  const int gids[4] = {g4.x, g4.y, g4.z, g4.w};
  const int sids[4] = {s4.x, s4.y, s4.z, s4.w};
  const int cids[4] = {c4.x, c4.y, c4.z, c4.w};
  int myscore[4];
  #pragma unroll
  for (int j = 0; j < 4; ++j) {
    int sc;
    const int gid = gids[j];
    if (gid == 0) {
      sc = -1;  // masked (reference: -inf)
    } else {
      const float4* pg = (const float4*)(P + (size_t)gid * 48);
      const float4* ps = (const float4*)(P + (size_t)sids[j] * 48 + 16);
      const float4* pc = (const float4*)(P + (size_t)cids[j] * 48 + 32);
      sc = 0;
      #pragma unroll
      for (int q = 0; q < 4; ++q) {
        const float4 a = pg[q], bb = ps[q], c = pc[q];
        const float dx = a.x + bb.x + c.x;
        const float dy = a.y + bb.y + c.y;
        const float dz = a.z + bb.z + c.z;
        const float dw = a.w + bb.w + c.w;
        sc += ((dx > 0.f ? 1 : (dx < 0.f ? -1 : 0)) == icode[q * 4 + 0]);
        sc += ((dy > 0.f ? 1 : (dy < 0.f ? -1 : 0)) == icode[q * 4 + 1]);
        sc += ((dz > 0.f ? 1 : (dz < 0.f ? -1 : 0)) == icode[q * 4 + 2]);
        sc += ((dw > 0.f ? 1 : (dw < 0.f ? -1 : 0)) == icode[q * 4 + 3]);
      }
    }
    myscore[j] = sc;
    scores[base_l + j] = (signed char)sc;
    atomicAdd(&hist[sc + 1], 1);
  }
  __syncthreads();

  // ---- threshold: all threads compute identically from the histogram ----
  int above = 0, tval = -1, need = 0;
  for (int s = 16; s >= -1; --s) {
    const int c = hist[s + 1];
    if (above + c >= TOPKx) { tval = s; need = TOPKx - above; break; }
    above += c;
  }

  // ---- tie ranking: per-thread counts + block exclusive scan (asc. index) ----
  int cnt = 0;
  #pragma unroll
  for (int j = 0; j < 4; ++j) cnt += (myscore[j] == tval) ? 1 : 0;
  int v = cnt;
  const int lane = tid & 63, wave = tid >> 6;
  #pragma unroll
  for (int o = 1; o < 64; o <<= 1) {
    const int u = __shfl_up(v, o, 64);
    if (lane >= o) v += u;
  }
  if (lane == 63) wsum[wave] = v;
  __syncthreads();
  int rank = v - cnt;
  for (int w = 0; w < wave; ++w) rank += wsum[w];

  #pragma unroll
  for (int j = 0; j < 4; ++j) {
    const int l = base_l + j;
    const int s = myscore[j];
    if (s > tval) {
      const int slot = atomicAdd(&cnt_above, 1);
      sel[b * TOPKx + slot] = l;
    } else if (s == tval) {
      if (rank < need) sel[b * TOPKx + above + rank] = l;
      ++rank;
    }
  }
}

// ---------------------------------------------------------------------------
// Kernel 2: MHA. 256 threads: waves 0-1 = kh+score, waves 2-3 = vh.
// ---------------------------------------------------------------------------
template<int K, int STRIDE, bool IS_LONG>
__global__ __launch_bounds__(256) void k_mha(
    const int* __restrict__ kg, const int* __restrict__ ks, const int* __restrict__ kc,
    const int* __restrict__ ig, const int* __restrict__ ish, const int* __restrict__ ici,
    const float* __restrict__ emb,
    const float* __restrict__ Wq, const float* __restrict__ bq,
    const float* __restrict__ Wk, const float* __restrict__ bk,
    const float* __restrict__ Wv, const float* __restrict__ bv,
    const float* __restrict__ Wo, const float* __restrict__ bo,
    const int* __restrict__ sel,
    float* __restrict__ outv)
{
  __shared__ float Xitem[48];
  __shared__ float qh[48];
  __shared__ __align__(16) float vhs[K][48];
  __shared__ float scs[8][K + 4];
  __shared__ float osm[48];
  __shared__ unsigned char validf[K];
  const int b = blockIdx.x, tid = threadIdx.x;
  const int role = tid >> 7;      // wave-uniform: 0 = kh+score, 1 = vh
  const int p = tid & 127;

  if (tid < 48) {
    const int seg = tid >> 4, e = tid & 15;
    const int id = (seg == 0) ? ig[b] : (seg == 1) ? ish[b] : ici[b];
    Xitem[tid] = emb[(size_t)id * 16 + e];
  }
  __syncthreads();
  if (tid < 48) {
    float a = bq[tid];
    for (int e = 0; e < 48; ++e) a += Xitem[e] * Wq[e * 48 + tid];
    qh[tid] = a;
  }

  int gid = 0, sid = 0, cid = 0;
  if (p < K) {
    const int pos = IS_LONG ? sel[b * TOPKx + p] : p;
    const size_t off = (size_t)b * STRIDE + pos;
    gid = kg[off]; sid = ks[off]; cid = kc[off];
  }
  // barrier (qh now visible) + count valid (role-0 half only -> each pos once)
  const int nval = __syncthreads_count(role == 0 && p < K && gid != 0);

  if (p < K) {
    float acc[48];
    const float* Wm = (role == 0) ? Wk : Wv;
    const float* bm = (role == 0) ? bk : bv;
    #pragma unroll
    for (int j = 0; j < 48; ++j) acc[j] = bm[j];
    const int ids3[3] = {gid, sid, cid};
    #pragma unroll
    for (int seg = 0; seg < 3; ++seg) {
      const float* row = emb + (size_t)ids3[seg] * 16;
      #pragma unroll
      for (int i4 = 0; i4 < 4; ++i4) {
        const float4 xv = ((const float4*)row)[i4];
        const float xs[4] = {xv.x, xv.y, xv.z, xv.w};
        #pragma unroll
        for (int c = 0; c < 4; ++c) {
          const int e = seg * 16 + i4 * 4 + c;   // uniform -> scalar W loads
          const float* wr = Wm + e * 48;
          const float xe = xs[c];
          #pragma unroll
          for (int j = 0; j < 48; ++j) acc[j] += xe * wr[j];
        }
      }
    }
    if (role == 0) {
      // short: mask is position < slen; long: mask is gid != 0 on selected
      validf[p] = IS_LONG ? (unsigned char)(gid != 0) : (unsigned char)(p < nval);
      #pragma unroll
      for (int h = 0; h < 8; ++h) {
        float s = 0.f;
        #pragma unroll
        for (int d = 0; d < 6; ++d) s += qh[h * 6 + d] * acc[h * 6 + d];
        scs[h][p] = s * 0.40824829046386301637f;   // 1/sqrt(6)
      }
    } else {
      #pragma unroll
      for (int j = 0; j < 48; ++j) vhs[p][j] = acc[j];
    }
  }
  __syncthreads();

  // ---- softmax: 8 groups of 16 lanes, one head each ----
  if (tid < 128) {
    const int h = tid >> 4, l16 = tid & 15;
    float amax = -INFINITY;
    for (int k = l16; k < K; k += 16) if (validf[k]) amax = fmaxf(amax, scs[h][k]);
    #pragma unroll
    for (int m = 1; m < 16; m <<= 1) amax = fmaxf(amax, __shfl_xor(amax, m, 16));
    if (nval == 0) {
      // reference: all entries get -1e9 -> fp32 rounds equal -> uniform weights
      for (int k = l16; k < K; k += 16) scs[h][k] = 1.0f / (float)K;
    } else {
      float ssum = 0.f;
      for (int k = l16; k < K; k += 16) {
        const float ev = validf[k] ? expf(scs[h][k] - amax) : 0.f;
        scs[h][k] = ev;
        ssum += ev;
      }
      #pragma unroll
      for (int m = 1; m < 16; m <<= 1) ssum += __shfl_xor(ssum, m, 16);
      const float inv = 1.0f / ssum;
      for (int k = l16; k < K; k += 16) scs[h][k] *= inv;
    }
  }
  __syncthreads();

  if (tid < 48) {
    const int h = tid / 6;
    float a = 0.f;
    for (int k = 0; k < K; ++k) a += scs[h][k] * vhs[k][tid];
    osm[tid] = a;
  }
  __syncthreads();
  if (tid < 48) {
    float r = bo[tid];
    for (int j = 0; j < 48; ++j) r += osm[j] * Wo[j * 48 + tid];
    outv[b * 48 + tid] = r;
  }
}

// ---------------------------------------------------------------------------
// Kernel 3: MLP head (one block per batch elem)
// ---------------------------------------------------------------------------
__device__ __forceinline__ float block_sum256(float v, float* red) {
  #pragma unroll
  for (int m = 32; m >= 1; m >>= 1) v += __shfl_xor(v, m, 64);
  const int lane = threadIdx.x & 63, wave = threadIdx.x >> 6;
  if (lane == 0) red[wave] = v;
  __syncthreads();
  const float t = red[0] + red[1] + red[2] + red[3];
  __syncthreads();
  return t;
}

__global__ __launch_bounds__(256) void k_mlp(
    const int* __restrict__ uid, const int* __restrict__ u1, const int* __restrict__ u2,
    const int* __restrict__ u3, const int* __restrict__ u4,
    const int* __restrict__ ig, const int* __restrict__ ish, const int* __restrict__ ici,
    const float* __restrict__ emb,
    const float* __restrict__ sint, const float* __restrict__ lint,
    const float* __restrict__ W1, const float* __restrict__ b1,
    const float* __restrict__ g1, const float* __restrict__ be1,
    const float* __restrict__ W2, const float* __restrict__ b2,
    const float* __restrict__ g2, const float* __restrict__ be2,
    const float* __restrict__ W3, const float* __restrict__ b3,
    float* __restrict__ out)
{
  __shared__ __align__(16) float x[224];
  __shared__ __align__(16) float h1[200];
  __shared__ float h2[80];
  __shared__ float red[4];
  const int b = blockIdx.x, tid = threadIdx.x;

  if (tid < 128) {
    const int e = tid & 15;
    int id;
    if (tid < 48) {
      const int seg = tid >> 4;
      id = (seg == 0) ? ig[b] : (seg == 1) ? ish[b] : ici[b];
    } else {
      const int f = (tid - 48) >> 4;
      id = (f == 0) ? uid[b] : (f == 1) ? u1[b] : (f == 2) ? u2[b] : (f == 3) ? u3[b] : u4[b];
    }
    x[tid] = emb[(size_t)id * 16 + e];
  } else if (tid < 176) {
    x[tid] = sint[b * 48 + (tid - 128)];
  } else if (tid < 224) {
    x[tid] = lint[b * 48 + (tid - 176)];
  }
  __syncthreads();

  float v = 0.f;
  if (tid < 200) {
    v = b1[tid];
    for (int i4 = 0; i4 < 56; ++i4) {
      const float4 xv = *(const float4*)(x + i4 * 4);
      const float* w = W1 + i4 * 4 * 200 + tid;
      v += xv.x * w[0];
      v += xv.y * w[200];
      v += xv.z * w[400];
      v += xv.w * w[600];
    }
  }
  const float mean1 = block_sum256((tid < 200) ? v : 0.f, red) * (1.0f / 200.0f);
  const float dv = (tid < 200) ? (v - mean1) : 0.f;
  const float var1 = block_sum256(dv * dv, red) * (1.0f / 200.0f);
  if (tid < 200) {
    const float y = (v - mean1) * rsqrtf(var1 + 1e-3f) * g1[tid] + be1[tid];
    h1[tid] = fmaxf(y, 0.f);
  }
  __syncthreads();

  float v2 = 0.f;
  if (tid < 80) {
    v2 = b2[tid];
    for (int i4 = 0; i4 < 50; ++i4) {
      const float4 xv = *(const float4*)(h1 + i4 * 4);
      const float* w = W2 + i4 * 4 * 80 + tid;
      v2 += xv.x * w[0];
      v2 += xv.y * w[80];
      v2 += xv.z * w[160];
      v2 += xv.w * w[240];
    }
  }
  const float mean2 = block_sum256((tid < 80) ? v2 : 0.f, red) * (1.0f / 80.0f);
  const float dv2 = (tid < 80) ? (v2 - mean2) : 0.f;
  const float var2 = block_sum256(dv2 * dv2, red) * (1.0f / 80.0f);
  if (tid < 80) {
    const float y = (v2 - mean2) * rsqrtf(var2 + 1e-3f) * g2[tid] + be2[tid];
    h2[tid] = fmaxf(y, 0.f);
  }
  __syncthreads();

  const float p = (tid < 80) ? h2[tid] * W3[tid] : 0.f;
  const float z = block_sum256(p, red);
  if (tid == 0) {
    out[b] = 1.0f / (1.0f + expf(-(z + b3[0])));
  }
}

// ---------------------------------------------------------------------------
extern "C" void kernel_launch(void* const* d_in, const int* in_sizes, int n_in,
                              void* d_out, int out_size, void* d_ws, size_t ws_size,
                              hipStream_t stream) {
  (void)in_sizes; (void)n_in; (void)out_size; (void)ws_size;
  const int* uid = (const int*)d_in[0];
  const int* u1  = (const int*)d_in[1];
  const int* u2  = (const int*)d_in[2];
  const int* u3  = (const int*)d_in[3];
  const int* u4  = (const int*)d_in[4];
  const int* ig  = (const int*)d_in[5];
  const int* ish = (const int*)d_in[6];
  const int* ici = (const int*)d_in[7];
  const int* sg  = (const int*)d_in[8];
  const int* ss  = (const int*)d_in[9];
  const int* scd = (const int*)d_in[10];
  const int* lg  = (const int*)d_in[11];
  const int* ls  = (const int*)d_in[12];
  const int* lcd = (const int*)d_in[13];
  const float* emb = (const float*)d_in[14];
  const float* Hm  = (const float*)d_in[15];
  const float* sWq = (const float*)d_in[16];
  const float* sbq = (const float*)d_in[17];
  const float* sWk = (const float*)d_in[18];
  const float* sbk = (const float*)d_in[19];
  const float* sWv = (const float*)d_in[20];
  const float* sbv = (const float*)d_in[21];
  const float* sWo = (const float*)d_in[22];
  const float* sbo = (const float*)d_in[23];
  const float* lWq = (const float*)d_in[24];
  const float* lbq = (const float*)d_in[25];
  const float* lWk = (const float*)d_in[26];
  const float* lbk = (const float*)d_in[27];
  const float* lWv = (const float*)d_in[28];
  const float* lbv = (const float*)d_in[29];
  const float* lWo = (const float*)d_in[30];
  const float* lbo = (const float*)d_in[31];
  const float* W1 = (const float*)d_in[32];
  const float* b1 = (const float*)d_in[33];
  const float* g1 = (const float*)d_in[34];
  const float* be1 = (const float*)d_in[35];
  const float* W2 = (const float*)d_in[36];
  const float* b2 = (const float*)d_in[37];
  const float* g2 = (const float*)d_in[38];
  const float* be2 = (const float*)d_in[39];
  const float* W3 = (const float*)d_in[40];
  const float* b3 = (const float*)d_in[41];
  float* out = (float*)d_out;

  int* sel = (int*)d_ws;                       //  196,608 B
  float* sint = (float*)d_ws + BB * TOPKx;     //  196,608 B
  float* lint = sint + BB * 48;                //  196,608 B
  float* P = lint + BB * 48;                   // 30,720,000 B  (total ~31.3 MB)

  k_partial<<<dim3((VOCABx * 48 + 255) / 256), dim3(256), 0, stream>>>(emb, Hm, P);
  k_score_topk<<<dim3(BB), dim3(512), 0, stream>>>(lg, ls, lcd, ig, ish, ici, P, sel);
  k_mha<128, 128, false><<<dim3(BB), dim3(256), 0, stream>>>(
      sg, ss, scd, ig, ish, ici, emb,
      sWq, sbq, sWk, sbk, sWv, sbv, sWo, sbo, (const int*)nullptr, sint);
  k_mha<48, 2048, true><<<dim3(BB), dim3(256), 0, stream>>>(
      lg, ls, lcd, ig, ish, ici, emb,
      lWq, lbq, lWk, lbk, lWv, lbv, lWo, lbo, sel, lint);
  k_mlp<<<dim3(BB), dim3(256), 0, stream>>>(
      uid, u1, u2, u3, u4, ig, ish, ici, emb,
      sint, lint, W1, b1, g1, be1, W2, b2, g2, be2, W3, b3, out);
}

// Round 3
// 342.466 us; speedup vs baseline: 1.2380x; 1.2380x over previous
//
#include <hip/hip_runtime.h>
#include <hip/hip_fp16.h>
#include <math.h>

#define BB 1024
#define LSx 128
#define LLx 2048
#define TOPKx 48
#define VOCABx 160000

// ---------------------------------------------------------------------------
// Kernel A: precompute partial LSH projections (fp16 storage)
//   Ph[v][seg][m] = sum_e emb[v][e] * H[seg*16+e][m]
// ---------------------------------------------------------------------------
__global__ __launch_bounds__(256) void k_partial(
    const float* __restrict__ emb, const float* __restrict__ Hm,
    __half* __restrict__ Ph)
{
  const int idx = blockIdx.x * 256 + threadIdx.x;   // = v*48 + seg*16 + m
  if (idx >= VOCABx * 48) return;
  const int v = idx / 48;
  const int r = idx - v * 48;
  const int seg = r >> 4, m = r & 15;
  const float* er = emb + (size_t)v * 16;
  float a = 0.f;
  #pragma unroll
  for (int e = 0; e < 16; ++e) a += er[e] * Hm[(seg * 16 + e) * 16 + m];
  Ph[idx] = __float2half(a);
}

// ---------------------------------------------------------------------------
// Kernel B: LSH scoring + top-k. 512 threads; 16-lane group per position:
// lane m loads Ph element m of each segment -> 3 lines/position, ballot score.
// ---------------------------------------------------------------------------
__global__ __launch_bounds__(512) void k_score_topk(
    const int* __restrict__ lg, const int* __restrict__ lsh, const int* __restrict__ lc,
    const int* __restrict__ ig, const int* __restrict__ ish, const int* __restrict__ ici,
    const float* __restrict__ emb, const float* __restrict__ Hm,
    const __half* __restrict__ Ph,
    int* __restrict__ sel)
{
  __shared__ int idsL[3 * LLx];          // 24 KB
  __shared__ signed char scores[LLx];    // 2 KB
  __shared__ float Xitem[48];
  __shared__ int icodeS[16];
  __shared__ int hist[18];
  __shared__ int cnt_above;
  __shared__ int wsum[8];
  const int b = blockIdx.x, tid = threadIdx.x;

  // stage ids (coalesced int4: 512 threads x 4 = 2048 per array)
  ((int4*)idsL)[tid]        = ((const int4*)(lg  + (size_t)b * LLx))[tid];
  ((int4*)idsL)[512 + tid]  = ((const int4*)(lsh + (size_t)b * LLx))[tid];
  ((int4*)idsL)[1024 + tid] = ((const int4*)(lc  + (size_t)b * LLx))[tid];
  if (tid < 48) {
    const int seg = tid >> 4, e = tid & 15;
    const int id = (seg == 0) ? ig[b] : (seg == 1) ? ish[b] : ici[b];
    Xitem[tid] = emb[(size_t)id * 16 + e];
  }
  if (tid < 18) hist[tid] = 0;
  if (tid == 0) cnt_above = 0;
  __syncthreads();
  if (tid < 16) {  // exact fp32 item code (affects all positions of this b)
    float dd = 0.f;
    for (int e = 0; e < 48; ++e) dd += Xitem[e] * Hm[e * 16 + tid];
    icodeS[tid] = (dd > 0.f) ? 1 : (dd < 0.f ? -1 : 0);
  }
  __syncthreads();

  const int l16 = tid & 15;
  const int grpw = (tid >> 4) & 3;   // group within wave (0..3)
  const int grp32 = tid >> 4;        // group within block (0..31)
  const int myic = icodeS[l16];

  for (int r4 = 0; r4 < 64; r4 += 4) {
    int g_[4], s_[4], c_[4];
    #pragma unroll
    for (int u = 0; u < 4; ++u) {
      const int p = (r4 + u) * 32 + grp32;
      g_[u] = idsL[p]; s_[u] = idsL[LLx + p]; c_[u] = idsL[2 * LLx + p];
    }
    float d0[4], d1[4], d2[4];
    #pragma unroll
    for (int u = 0; u < 4; ++u) {
      d0[u] = __half2float(Ph[(size_t)g_[u] * 48 + l16]);
      d1[u] = __half2float(Ph[(size_t)s_[u] * 48 + 16 + l16]);
      d2[u] = __half2float(Ph[(size_t)c_[u] * 48 + 32 + l16]);
    }
    #pragma unroll
    for (int u = 0; u < 4; ++u) {
      const int p = (r4 + u) * 32 + grp32;
      const float d = (d0[u] + d1[u]) + d2[u];
      const int cs = (d > 0.f) ? 1 : (d < 0.f ? -1 : 0);
      const unsigned long long bal = __ballot(cs == myic);
      int sc = (int)__popcll((bal >> (16 * grpw)) & 0xFFFFull);
      if (g_[u] == 0) sc = -1;   // masked (reference: -inf)
      if (l16 == 0) {
        scores[p] = (signed char)sc;
        atomicAdd(&hist[sc + 1], 1);
      }
    }
  }
  __syncthreads();

  // ---- threshold (identical on all threads) ----
  int above = 0, tval = -1, need = 0;
  for (int s = 16; s >= -1; --s) {
    const int c = hist[s + 1];
    if (above + c >= TOPKx) { tval = s; need = TOPKx - above; break; }
    above += c;
  }

  // ---- tie ranking: 4 consecutive positions per thread + block scan ----
  const int base_l = tid * 4;
  int myscore[4];
  #pragma unroll
  for (int j = 0; j < 4; ++j) myscore[j] = scores[base_l + j];
  int cnt = 0;
  #pragma unroll
  for (int j = 0; j < 4; ++j) cnt += (myscore[j] == tval) ? 1 : 0;
  int v = cnt;
  const int lane = tid & 63, wave = tid >> 6;
  #pragma unroll
  for (int o = 1; o < 64; o <<= 1) {
    const int u = __shfl_up(v, o, 64);
    if (lane >= o) v += u;
  }
  if (lane == 63) wsum[wave] = v;
  __syncthreads();
  int rank = v - cnt;
  for (int w = 0; w < wave; ++w) rank += wsum[w];

  #pragma unroll
  for (int j = 0; j < 4; ++j) {
    const int l = base_l + j;
    const int s = myscore[j];
    if (s > tval) {
      const int slot = atomicAdd(&cnt_above, 1);
      sel[b * TOPKx + slot] = l;
    } else if (s == tval) {
      if (rank < need) sel[b * TOPKx + above + rank] = l;
      ++rank;
    }
  }
}

// ---------------------------------------------------------------------------
// kv projection helper: W/bvec are compile-time-distinct SGPR pointers at each
// inline site -> addresses stay SGPR-pure -> s_load through constant cache.
// ---------------------------------------------------------------------------
__device__ __forceinline__ void kv_accum(
    const float* __restrict__ W, const float* __restrict__ bvec,
    int gid, int sid, int cid, const float* __restrict__ emb, float acc[48])
{
  #pragma unroll
  for (int j = 0; j < 48; ++j) acc[j] = bvec[j];
  const int ids3[3] = {gid, sid, cid};
  #pragma unroll
  for (int seg = 0; seg < 3; ++seg) {
    const float* row = emb + (size_t)ids3[seg] * 16;
    #pragma unroll
    for (int i4 = 0; i4 < 4; ++i4) {
      const float4 xv = ((const float4*)row)[i4];
      const float xs[4] = {xv.x, xv.y, xv.z, xv.w};
      #pragma unroll
      for (int c = 0; c < 4; ++c) {
        const int e = seg * 16 + i4 * 4 + c;
        const float* wr = W + e * 48;
        const float xe = xs[c];
        #pragma unroll
        for (int j = 0; j < 48; ++j) acc[j] += xe * wr[j];
      }
    }
  }
}

// ---------------------------------------------------------------------------
// Kernel 2: MHA. 256 threads: waves 0-1 = kh+score, waves 2-3 = vh.
// ---------------------------------------------------------------------------
template<int K, int STRIDE, bool IS_LONG>
__global__ __launch_bounds__(256) void k_mha(
    const int* __restrict__ kg, const int* __restrict__ ks, const int* __restrict__ kc,
    const int* __restrict__ ig, const int* __restrict__ ish, const int* __restrict__ ici,
    const float* __restrict__ emb,
    const float* __restrict__ Wq, const float* __restrict__ bq,
    const float* __restrict__ Wk, const float* __restrict__ bk,
    const float* __restrict__ Wv, const float* __restrict__ bv,
    const float* __restrict__ Wo, const float* __restrict__ bo,
    const int* __restrict__ sel,
    float* __restrict__ outv)
{
  __shared__ float Xitem[48];
  __shared__ float qh[48];
  __shared__ __align__(16) float vhs[K][48];
  __shared__ float scs[8][K + 4];
  __shared__ float osm[48];
  __shared__ unsigned char validf[K];
  const int b = blockIdx.x, tid = threadIdx.x;
  const int role = tid >> 7;      // wave-uniform: 0 = kh+score, 1 = vh
  const int p = tid & 127;

  if (tid < 48) {
    const int seg = tid >> 4, e = tid & 15;
    const int id = (seg == 0) ? ig[b] : (seg == 1) ? ish[b] : ici[b];
    Xitem[tid] = emb[(size_t)id * 16 + e];
  }
  __syncthreads();
  if (tid < 48) {
    float a = bq[tid];
    for (int e = 0; e < 48; ++e) a += Xitem[e] * Wq[e * 48 + tid];
    qh[tid] = a;
  }

  int gid = 0, sid = 0, cid = 0;
  if (p < K) {
    const int pos = IS_LONG ? sel[b * TOPKx + p] : p;
    const size_t off = (size_t)b * STRIDE + pos;
    gid = kg[off]; sid = ks[off]; cid = kc[off];
  }
  // barrier (qh now visible) + count valid (role-0 half only -> each pos once)
  const int nval = __syncthreads_count(role == 0 && p < K && gid != 0);

  if (p < K) {
    if (role == 0) {
      float acc[48];
      kv_accum(Wk, bk, gid, sid, cid, emb, acc);
      // short: mask is position < slen; long: mask is gid != 0 on selected
      validf[p] = IS_LONG ? (unsigned char)(gid != 0) : (unsigned char)(p < nval);
      #pragma unroll
      for (int h = 0; h < 8; ++h) {
        float s = 0.f;
        #pragma unroll
        for (int d = 0; d < 6; ++d) s += qh[h * 6 + d] * acc[h * 6 + d];
        scs[h][p] = s * 0.40824829046386301637f;   // 1/sqrt(6)
      }
    } else {
      float acc[48];
      kv_accum(Wv, bv, gid, sid, cid, emb, acc);
      #pragma unroll
      for (int j = 0; j < 48; ++j) vhs[p][j] = acc[j];
    }
  }
  __syncthreads();

  // ---- softmax: 8 groups of 16 lanes, one head each ----
  if (tid < 128) {
    const int h = tid >> 4, l16 = tid & 15;
    float amax = -INFINITY;
    for (int k = l16; k < K; k += 16) if (validf[k]) amax = fmaxf(amax, scs[h][k]);
    #pragma unroll
    for (int m = 1; m < 16; m <<= 1) amax = fmaxf(amax, __shfl_xor(amax, m, 16));
    if (nval == 0) {
      // reference: all entries get -1e9 -> fp32 rounds equal -> uniform weights
      for (int k = l16; k < K; k += 16) scs[h][k] = 1.0f / (float)K;
    } else {
      float ssum = 0.f;
      for (int k = l16; k < K; k += 16) {
        const float ev = validf[k] ? expf(scs[h][k] - amax) : 0.f;
        scs[h][k] = ev;
        ssum += ev;
      }
      #pragma unroll
      for (int m = 1; m < 16; m <<= 1) ssum += __shfl_xor(ssum, m, 16);
      const float inv = 1.0f / ssum;
      for (int k = l16; k < K; k += 16) scs[h][k] *= inv;
    }
  }
  __syncthreads();

  if (tid < 48) {
    const int h = tid / 6;
    float a = 0.f;
    for (int k = 0; k < K; ++k) a += scs[h][k] * vhs[k][tid];
    osm[tid] = a;
  }
  __syncthreads();
  if (tid < 48) {
    float r = bo[tid];
    for (int j = 0; j < 48; ++j) r += osm[j] * Wo[j * 48 + tid];
    outv[b * 48 + tid] = r;
  }
}

// ---------------------------------------------------------------------------
// Kernel 3: MLP head (one block per batch elem)
// ---------------------------------------------------------------------------
__device__ __forceinline__ float block_sum256(float v, float* red) {
  #pragma unroll
  for (int m = 32; m >= 1; m >>= 1) v += __shfl_xor(v, m, 64);
  const int lane = threadIdx.x & 63, wave = threadIdx.x >> 6;
  if (lane == 0) red[wave] = v;
  __syncthreads();
  const float t = red[0] + red[1] + red[2] + red[3];
  __syncthreads();
  return t;
}

__global__ __launch_bounds__(256) void k_mlp(
    const int* __restrict__ uid, const int* __restrict__ u1, const int* __restrict__ u2,
    const int* __restrict__ u3, const int* __restrict__ u4,
    const int* __restrict__ ig, const int* __restrict__ ish, const int* __restrict__ ici,
    const float* __restrict__ emb,
    const float* __restrict__ sint, const float* __restrict__ lint,
    const float* __restrict__ W1, const float* __restrict__ b1,
    const float* __restrict__ g1, const float* __restrict__ be1,
    const float* __restrict__ W2, const float* __restrict__ b2,
    const float* __restrict__ g2, const float* __restrict__ be2,
    const float* __restrict__ W3, const float* __restrict__ b3,
    float* __restrict__ out)
{
  __shared__ __align__(16) float x[224];
  __shared__ __align__(16) float h1[200];
  __shared__ float h2[80];
  __shared__ float red[4];
  const int b = blockIdx.x, tid = threadIdx.x;

  if (tid < 128) {
    const int e = tid & 15;
    int id;
    if (tid < 48) {
      const int seg = tid >> 4;
      id = (seg == 0) ? ig[b] : (seg == 1) ? ish[b] : ici[b];
    } else {
      const int f = (tid - 48) >> 4;
      id = (f == 0) ? uid[b] : (f == 1) ? u1[b] : (f == 2) ? u2[b] : (f == 3) ? u3[b] : u4[b];
    }
    x[tid] = emb[(size_t)id * 16 + e];
  } else if (tid < 176) {
    x[tid] = sint[b * 48 + (tid - 128)];
  } else if (tid < 224) {
    x[tid] = lint[b * 48 + (tid - 176)];
  }
  __syncthreads();

  float v = 0.f;
  if (tid < 200) {
    float a0 = b1[tid], a1 = 0.f, a2 = 0.f, a3 = 0.f;
    for (int i4 = 0; i4 < 56; ++i4) {
      const float4 xv = *(const float4*)(x + i4 * 4);
      const float* w = W1 + i4 * 4 * 200 + tid;
      a0 += xv.x * w[0];
      a1 += xv.y * w[200];
      a2 += xv.z * w[400];
      a3 += xv.w * w[600];
    }
    v = (a0 + a1) + (a2 + a3);
  }
  const float mean1 = block_sum256((tid < 200) ? v : 0.f, red) * (1.0f / 200.0f);
  const float dv = (tid < 200) ? (v - mean1) : 0.f;
  const float var1 = block_sum256(dv * dv, red) * (1.0f / 200.0f);
  if (tid < 200) {
    const float y = (v - mean1) * rsqrtf(var1 + 1e-3f) * g1[tid] + be1[tid];
    h1[tid] = fmaxf(y, 0.f);
  }
  __syncthreads();

  float v2 = 0.f;
  if (tid < 80) {
    float a0 = b2[tid], a1 = 0.f, a2 = 0.f, a3 = 0.f;
    for (int i4 = 0; i4 < 50; ++i4) {
      const float4 xv = *(const float4*)(h1 + i4 * 4);
      const float* w = W2 + i4 * 4 * 80 + tid;
      a0 += xv.x * w[0];
      a1 += xv.y * w[80];
      a2 += xv.z * w[160];
      a3 += xv.w * w[240];
    }
    v2 = (a0 + a1) + (a2 + a3);
  }
  const float mean2 = block_sum256((tid < 80) ? v2 : 0.f, red) * (1.0f / 80.0f);
  const float dv2 = (tid < 80) ? (v2 - mean2) : 0.f;
  const float var2 = block_sum256(dv2 * dv2, red) * (1.0f / 80.0f);
  if (tid < 80) {
    const float y = (v2 - mean2) * rsqrtf(var2 + 1e-3f) * g2[tid] + be2[tid];
    h2[tid] = fmaxf(y, 0.f);
  }
  __syncthreads();

  const float p = (tid < 80) ? h2[tid] * W3[tid] : 0.f;
  const float z = block_sum256(p, red);
  if (tid == 0) {
    out[b] = 1.0f / (1.0f + expf(-(z + b3[0])));
  }
}

// ---------------------------------------------------------------------------
extern "C" void kernel_launch(void* const* d_in, const int* in_sizes, int n_in,
                              void* d_out, int out_size, void* d_ws, size_t ws_size,
                              hipStream_t stream) {
  (void)in_sizes; (void)n_in; (void)out_size; (void)ws_size;
  const int* uid = (const int*)d_in[0];
  const int* u1  = (const int*)d_in[1];
  const int* u2  = (const int*)d_in[2];
  const int* u3  = (const int*)d_in[3];
  const int* u4  = (const int*)d_in[4];
  const int* ig  = (const int*)d_in[5];
  const int* ish = (const int*)d_in[6];
  const int* ici = (const int*)d_in[7];
  const int* sg  = (const int*)d_in[8];
  const int* ss  = (const int*)d_in[9];
  const int* scd = (const int*)d_in[10];
  const int* lg  = (const int*)d_in[11];
  const int* ls  = (const int*)d_in[12];
  const int* lcd = (const int*)d_in[13];
  const float* emb = (const float*)d_in[14];
  const float* Hm  = (const float*)d_in[15];
  const float* sWq = (const float*)d_in[16];
  const float* sbq = (const float*)d_in[17];
  const float* sWk = (const float*)d_in[18];
  const float* sbk = (const float*)d_in[19];
  const float* sWv = (const float*)d_in[20];
  const float* sbv = (const float*)d_in[21];
  const float* sWo = (const float*)d_in[22];
  const float* sbo = (const float*)d_in[23];
  const float* lWq = (const float*)d_in[24];
  const float* lbq = (const float*)d_in[25];
  const float* lWk = (const float*)d_in[26];
  const float* lbk = (const float*)d_in[27];
  const float* lWv = (const float*)d_in[28];
  const float* lbv = (const float*)d_in[29];
  const float* lWo = (const float*)d_in[30];
  const float* lbo = (const float*)d_in[31];
  const float* W1 = (const float*)d_in[32];
  const float* b1 = (const float*)d_in[33];
  const float* g1 = (const float*)d_in[34];
  const float* be1 = (const float*)d_in[35];
  const float* W2 = (const float*)d_in[36];
  const float* b2 = (const float*)d_in[37];
  const float* g2 = (const float*)d_in[38];
  const float* be2 = (const float*)d_in[39];
  const float* W3 = (const float*)d_in[40];
  const float* b3 = (const float*)d_in[41];
  float* out = (float*)d_out;

  int* sel = (int*)d_ws;                       //  196,608 B
  float* sint = (float*)d_ws + BB * TOPKx;     //  196,608 B
  float* lint = sint + BB * 48;                //  196,608 B
  __half* Ph = (__half*)(lint + BB * 48);      // 15,360,000 B (total ~15.9 MB)

  k_partial<<<dim3((VOCABx * 48 + 255) / 256), dim3(256), 0, stream>>>(emb, Hm, Ph);
  k_score_topk<<<dim3(BB), dim3(512), 0, stream>>>(lg, ls, lcd, ig, ish, ici, emb, Hm, Ph, sel);
  k_mha<128, 128, false><<<dim3(BB), dim3(256), 0, stream>>>(
      sg, ss, scd, ig, ish, ici, emb,
      sWq, sbq, sWk, sbk, sWv, sbv, sWo, sbo, (const int*)nullptr, sint);
  k_mha<48, 2048, true><<<dim3(BB), dim3(256), 0, stream>>>(
      lg, ls, lcd, ig, ish, ici, emb,
      lWq, lbq, lWk, lbk, lWv, lbv, lWo, lbo, sel, lint);
  k_mlp<<<dim3(BB), dim3(256), 0, stream>>>(
      uid, u1, u2, u3, u4, ig, ish, ici, emb,
      sint, lint, W1, b1, g1, be1, W2, b2, g2, be2, W3, b3, out);
}